// Round 9
// baseline (211.814 us; speedup 1.0000x reference)
//
#include <hip/hip_runtime.h>
#include <hip/hip_bf16.h>

#define B_  256
#define H_  1024
#define D_  256
#define G_  32
#define C_  16
#define O_  256
#define HD_ 1280          // H + D
#define N1_ 16384         // C*H
#define RS_ 36            // LDS row stride in shorts (32 data + 4 pad = 72 B = 18
                          // banks -> 18*l16 mod 32 all-distinct -> 2-way (free);
                          // unpadded 64 B stride gave 8-way conflicts (4.2M cycles)

typedef __attribute__((ext_vector_type(8))) short short8;
typedef __attribute__((ext_vector_type(4))) short s16x4;
typedef __attribute__((ext_vector_type(4))) float f32x4;

#define MFMA16(a, b, c) __builtin_amdgcn_mfma_f32_16x16x32_bf16((a), (b), (c), 0, 0, 0)

// tanh via fast exp + hw rcp; clamped to +-(1-6e-8) so that the downstream
// blend denominator 1 + tA*tB is always > 0 (never 0*inf = NaN).
__device__ __forceinline__ float tanh_c(float x) {
    float y = __expf(2.f * x);
    float t = 1.f - 2.f * __builtin_amdgcn_rcpf(y + 1.f);
    return fminf(fmaxf(t, -0.99999994f), 0.99999994f);
}

// Split fp32 into bf16 hi + bf16 lo (both truncated).
__device__ __forceinline__ short bfhi(float x) {
    return (short)(__float_as_uint(x) >> 16);
}
__device__ __forceinline__ short bflo(float x) {
    float fhi = __uint_as_float(__float_as_uint(x) & 0xFFFF0000u);
    return (short)(__float_as_uint(x - fhi) >> 16);
}

__device__ __forceinline__ void split4(const float4 v, s16x4& hi, s16x4& lo) {
    hi[0] = bfhi(v.x); lo[0] = bflo(v.x);
    hi[1] = bfhi(v.y); lo[1] = bflo(v.y);
    hi[2] = bfhi(v.z); lo[2] = bflo(v.z);
    hi[3] = bfhi(v.w); lo[3] = bflo(v.w);
}

// ---------------------------------------------------------------------------
// Kernel 1: tA[b, c*H+o] = tanh( sum_h hidden[b,h]*attn_w[c,o,h] + attn_b[c,o] )
// GEMM: M=256, N=16384, K=1024, fp32 in/out, 3-term bf16-split MFMA.
// 128(M)x64(N) tile, 512 threads (8 waves, 4m x 2n, wave 32x32), grid (2,256).
// LDS rows padded to RS_=36 shorts to kill the 8-way read bank conflicts.
// ---------------------------------------------------------------------------
__global__ __launch_bounds__(512) void gemm1_kernel(
    const float* __restrict__ hidden, const float* __restrict__ attn_w,
    const float* __restrict__ attn_b, float* __restrict__ hp)
{
    __shared__ short AsH[128 * RS_];   // [row][k], padded stride
    __shared__ short AsL[128 * RS_];
    __shared__ short BsH[64 * RS_];
    __shared__ short BsL[64 * RS_];

    const int tid  = threadIdx.x;
    const int wave = tid >> 6, lane = tid & 63;
    const int m0 = blockIdx.x * 128;   // 2 m-tiles (fast axis)
    const int n0 = blockIdx.y * 64;    // 256 n-tiles
    const int wm = (wave >> 1) * 32;   // 4x2 wave grid, each wave 32x32
    const int wn = (wave & 1) * 32;
    const int l16 = lane & 15;
    const int lk  = (lane >> 4) * 8;

    f32x4 acc[2][2];
    for (int mi = 0; mi < 2; ++mi)
        for (int ni = 0; ni < 2; ++ni)
            acc[mi][ni] = f32x4{0.f, 0.f, 0.f, 0.f};

    // A-tile: 128x32 = 1024 float4-chunks (2/thread); B-tile: 64x32 = 512 (1/thread)
    int rA[2], cA[2];
    #pragma unroll
    for (int i = 0; i < 2; ++i) {
        const int chunk = tid + i * 512;
        rA[i] = chunk >> 3;
        cA[i] = (chunk & 7) * 4;
    }
    const int rB = tid >> 3, cB = (tid & 7) * 4;

    for (int k0 = 0; k0 < H_; k0 += 32) {
        float4 va[2], vb;
        #pragma unroll
        for (int i = 0; i < 2; ++i)
            va[i] = *(const float4*)(hidden + (m0 + rA[i]) * H_ + k0 + cA[i]);
        vb = *(const float4*)(attn_w + (size_t)(n0 + rB) * HD_ + k0 + cB);

        __syncthreads();               // previous iter's fragment reads done
        #pragma unroll
        for (int i = 0; i < 2; ++i) {
            s16x4 h, l;
            split4(va[i], h, l);
            *(s16x4*)(AsH + rA[i] * RS_ + cA[i]) = h;
            *(s16x4*)(AsL + rA[i] * RS_ + cA[i]) = l;
        }
        {
            s16x4 h, l;
            split4(vb, h, l);
            *(s16x4*)(BsH + rB * RS_ + cB) = h;
            *(s16x4*)(BsL + rB * RS_ + cB) = l;
        }
        __syncthreads();               // stores visible to all waves

        short8 ah[2], al[2], bh[2], bl[2];
        #pragma unroll
        for (int mi = 0; mi < 2; ++mi) {
            ah[mi] = *(const short8*)(AsH + (wm + mi * 16 + l16) * RS_ + lk);
            al[mi] = *(const short8*)(AsL + (wm + mi * 16 + l16) * RS_ + lk);
        }
        #pragma unroll
        for (int ni = 0; ni < 2; ++ni) {
            bh[ni] = *(const short8*)(BsH + (wn + ni * 16 + l16) * RS_ + lk);
            bl[ni] = *(const short8*)(BsL + (wn + ni * 16 + l16) * RS_ + lk);
        }
        #pragma unroll
        for (int mi = 0; mi < 2; ++mi)
            #pragma unroll
            for (int ni = 0; ni < 2; ++ni) {
                acc[mi][ni] = MFMA16(ah[mi], bh[ni], acc[mi][ni]);
                acc[mi][ni] = MFMA16(al[mi], bh[ni], acc[mi][ni]);
                acc[mi][ni] = MFMA16(ah[mi], bl[ni], acc[mi][ni]);
            }
    }

    // C/D layout: col = lane&15, row = (lane>>4)*4 + reg.  Store tanh(val).
    const int lr = (lane >> 4) * 4;
    #pragma unroll
    for (int mi = 0; mi < 2; ++mi) {
        #pragma unroll
        for (int ni = 0; ni < 2; ++ni) {
            const int col  = n0 + wn + ni * 16 + l16;
            const float bias = attn_b[col];
            float* dst = hp + (size_t)(m0 + wm + mi * 16 + lr) * N1_ + col;
            f32x4 vacc = acc[mi][ni];
            dst[0]        = tanh_c(vacc[0] + bias);
            dst[N1_]      = tanh_c(vacc[1] + bias);
            dst[2 * N1_]  = tanh_c(vacc[2] + bias);
            dst[3 * N1_]  = tanh_c(vacc[3] + bias);
        }
    }
}

// ---------------------------------------------------------------------------
// Kernel 2: tB[c,g,o] = tanh( sum_d enc[c,g,d] * attn_w[c,o,H+d] )
// Per-c GEMM: M=32, N=1024, K=256; grid (16,16)=256 blocks.
// ---------------------------------------------------------------------------
__global__ __launch_bounds__(256) void gemm2_kernel(
    const float* __restrict__ enc, const float* __restrict__ attn_w,
    float* __restrict__ ep)
{
    const int tid  = threadIdx.x;
    const int wave = tid >> 6, lane = tid & 63;
    const int c  = blockIdx.y;
    const int n0 = blockIdx.x * 64 + wave * 16;   // o tile, 16 per wave
    const int l16 = lane & 15;
    const int lk  = (lane >> 4) * 8;

    f32x4 acc[2];
    acc[0] = f32x4{0.f, 0.f, 0.f, 0.f};
    acc[1] = f32x4{0.f, 0.f, 0.f, 0.f};

    const float* encp = enc + c * (G_ * D_);
    const float* wp   = attn_w + (size_t)c * H_ * HD_ + H_;

    #pragma unroll
    for (int kk = 0; kk < 8; ++kk) {
        const int k0 = kk * 32 + lk;
        short8 ah[2], al[2], bh, bl;
        #pragma unroll
        for (int mi = 0; mi < 2; ++mi) {
            const float* p = encp + (mi * 16 + l16) * D_ + k0;
            s16x4 h0, l0, h1, l1;
            split4(*(const float4*)p, h0, l0);
            split4(*(const float4*)(p + 4), h1, l1);
            ah[mi] = short8{h0[0],h0[1],h0[2],h0[3],h1[0],h1[1],h1[2],h1[3]};
            al[mi] = short8{l0[0],l0[1],l0[2],l0[3],l1[0],l1[1],l1[2],l1[3]};
        }
        {
            const float* p = wp + (size_t)(n0 + l16) * HD_ + k0;
            s16x4 h0, l0, h1, l1;
            split4(*(const float4*)p, h0, l0);
            split4(*(const float4*)(p + 4), h1, l1);
            bh = short8{h0[0],h0[1],h0[2],h0[3],h1[0],h1[1],h1[2],h1[3]};
            bl = short8{l0[0],l0[1],l0[2],l0[3],l1[0],l1[1],l1[2],l1[3]};
        }
        #pragma unroll
        for (int mi = 0; mi < 2; ++mi) {
            acc[mi] = MFMA16(ah[mi], bh, acc[mi]);
            acc[mi] = MFMA16(al[mi], bh, acc[mi]);
            acc[mi] = MFMA16(ah[mi], bl, acc[mi]);
        }
    }

    const int lr = (lane >> 4) * 4;
    #pragma unroll
    for (int mi = 0; mi < 2; ++mi) {
        const int g = mi * 16 + lr;
        const int o = n0 + l16;
        float* dst = ep + (c * G_ + g) * H_ + o;
        f32x4 vacc = acc[mi];
        dst[0]      = tanh_c(vacc[0]);
        dst[H_]     = tanh_c(vacc[1]);
        dst[2 * H_] = tanh_c(vacc[2]);
        dst[3 * H_] = tanh_c(vacc[3]);
    }
}

// ---------------------------------------------------------------------------
// Kernel 3: per (b,c): scores[g] = sum_h blend(tA,tB)*v where
// blend = (tA+tB)/(1+tA*tB) = tanh(A+B) exactly; softmax over g; att_cat out;
// weighted[b,c,d] = sum_g att*enc.  All fp32.
// ---------------------------------------------------------------------------
__global__ __launch_bounds__(256) void attn_kernel(
    const float* __restrict__ hp, const float* __restrict__ ep,
    const float* __restrict__ v, const float* __restrict__ enc,
    float* __restrict__ out, float* __restrict__ wt)
{
    const int c = blockIdx.x, b = blockIdx.y;
    const int tid  = threadIdx.x;
    const int wave = tid >> 6, lane = tid & 63;

    __shared__ float s_att[G_];
    __shared__ float s_sc[G_];

    float tav[16], vv[16];
    const float* hprow = hp + (size_t)b * N1_ + c * H_;
    const float* vrow  = v + c * H_;
    #pragma unroll
    for (int j = 0; j < 16; ++j) {
        const int o = lane + j * 64;
        tav[j] = hprow[o];
        vv[j]  = vrow[o];
    }

    #pragma unroll
    for (int gg = 0; gg < 8; ++gg) {
        const int g = wave * 8 + gg;
        const float* eprow = ep + (c * G_ + g) * H_;
        float s = 0.f;
        #pragma unroll
        for (int j = 0; j < 16; ++j) {
            const float tb  = eprow[lane + j * 64];
            const float ta  = tav[j];
            const float num = ta + tb;
            const float den = fmaf(ta, tb, 1.f);
            const float t   = num * __builtin_amdgcn_rcpf(den);
            s = fmaf(t, vv[j], s);
        }
        #pragma unroll
        for (int off = 32; off > 0; off >>= 1)
            s += __shfl_down(s, off, 64);
        if (lane == 0) s_sc[g] = s;
    }
    __syncthreads();

    if (tid < 32) {
        float s = s_sc[tid];
        float m = s;
        #pragma unroll
        for (int off = 16; off > 0; off >>= 1)
            m = fmaxf(m, __shfl_xor(m, off, 32));
        const float e = __expf(s - m);
        float sum = e;
        #pragma unroll
        for (int off = 16; off > 0; off >>= 1)
            sum += __shfl_xor(sum, off, 32);
        const float a = e / sum;
        s_att[tid] = a;
        out[(size_t)b * (C_ * G_) + c * G_ + tid] = a;   // att_cat
    }
    __syncthreads();

    // weighted[b,c,d], thread = d
    float wsum = 0.f;
    const float* encc = enc + c * (G_ * D_) + tid;
    #pragma unroll
    for (int g = 0; g < G_; ++g)
        wsum += s_att[g] * encc[g * D_];
    wt[(size_t)(b * C_ + c) * D_ + tid] = wsum;
}

// ---------------------------------------------------------------------------
// Kernel 4: pooled[b,d] = mean_c weighted; out[b,o] = pooled.out_w[o,:] + out_b
// ---------------------------------------------------------------------------
__global__ __launch_bounds__(256) void out_kernel(
    const float* __restrict__ wt, const float* __restrict__ out_w,
    const float* __restrict__ out_b, float* __restrict__ out)
{
    const int b = blockIdx.x, tid = threadIdx.x;
    __shared__ float pooled[D_];

    float s = 0.f;
    #pragma unroll
    for (int c = 0; c < C_; ++c)
        s += wt[(size_t)(b * C_ + c) * D_ + tid];
    pooled[tid] = s * (1.f / 16.f);
    __syncthreads();

    float acc = out_b[tid];
    const float* wrow = out_w + tid * D_;
    #pragma unroll 8
    for (int dc = 0; dc < 64; ++dc) {
        float4 w4 = *(const float4*)(wrow + dc * 4);
        acc += pooled[dc * 4 + 0] * w4.x;
        acc += pooled[dc * 4 + 1] * w4.y;
        acc += pooled[dc * 4 + 2] * w4.z;
        acc += pooled[dc * 4 + 3] * w4.w;
    }
    out[(size_t)B_ * (C_ * G_) + b * O_ + tid] = acc;
}

extern "C" void kernel_launch(void* const* d_in, const int* in_sizes, int n_in,
                              void* d_out, int out_size, void* d_ws, size_t ws_size,
                              hipStream_t stream) {
    const float* hidden = (const float*)d_in[0];   // (B,H)     fp32
    const float* enc    = (const float*)d_in[1];   // (C,G,D)   fp32
    const float* attn_w = (const float*)d_in[2];   // (C,H,H+D) fp32
    const float* attn_b = (const float*)d_in[3];   // (C,H)     fp32
    const float* v      = (const float*)d_in[4];   // (C,H)     fp32
    const float* out_w  = (const float*)d_in[5];   // (O,D)     fp32
    const float* out_b  = (const float*)d_in[6];   // (O,)      fp32
    float* out = (float*)d_out;                    // att_cat (B,C*G) ++ out (B,O)

    float* hp = (float*)d_ws;                      // (B, C*H)  tA, fp32: 16.78 MB
    float* ep = hp + (size_t)B_ * N1_;             // (C, G, H) tB, fp32:  2.10 MB
    float* wt = ep + (size_t)C_ * G_ * H_;         // (B, C, D) fp32:      4.19 MB

    gemm1_kernel<<<dim3(2, 256), 512, 0, stream>>>(hidden, attn_w, attn_b, hp);
    gemm2_kernel<<<dim3(16, C_), 256, 0, stream>>>(enc, attn_w, ep);
    attn_kernel<<<dim3(C_, B_), 256, 0, stream>>>(hp, ep, v, enc, out, wt);
    out_kernel<<<B_, 256, 0, stream>>>(wt, out_w, out_b, out);
}

// Round 10
// 207.656 us; speedup vs baseline: 1.0200x; 1.0200x over previous
//
#include <hip/hip_runtime.h>
#include <hip/hip_bf16.h>

#define B_  256
#define H_  1024
#define D_  256
#define G_  32
#define C_  16
#define O_  256
#define HD_ 1280          // H + D
#define N1_ 16384         // C*H
#define RS_ 36            // LDS row stride in shorts (72 B = 18 banks; uniform
                          // 2-way = free; 64 B stride was 8-way -> kept)

typedef __attribute__((ext_vector_type(8))) short short8;
typedef __attribute__((ext_vector_type(4))) short s16x4;
typedef __attribute__((ext_vector_type(4))) float f32x4;

#define MFMA16(a, b, c) __builtin_amdgcn_mfma_f32_16x16x32_bf16((a), (b), (c), 0, 0, 0)

// tanh via fast exp + hw rcp; clamped to +-(1-6e-8) so that the downstream
// blend denominator 1 + tA*tB is always > 0 (never 0*inf = NaN).
__device__ __forceinline__ float tanh_c(float x) {
    float y = __expf(2.f * x);
    float t = 1.f - 2.f * __builtin_amdgcn_rcpf(y + 1.f);
    return fminf(fmaxf(t, -0.99999994f), 0.99999994f);
}

// Split fp32 into bf16 hi + bf16 lo (both truncated).
__device__ __forceinline__ short bfhi(float x) {
    return (short)(__float_as_uint(x) >> 16);
}
__device__ __forceinline__ short bflo(float x) {
    float fhi = __uint_as_float(__float_as_uint(x) & 0xFFFF0000u);
    return (short)(__float_as_uint(x - fhi) >> 16);
}

__device__ __forceinline__ void split4(const float4 v, s16x4& hi, s16x4& lo) {
    hi[0] = bfhi(v.x); lo[0] = bflo(v.x);
    hi[1] = bfhi(v.y); lo[1] = bflo(v.y);
    hi[2] = bfhi(v.z); lo[2] = bflo(v.z);
    hi[3] = bfhi(v.w); lo[3] = bflo(v.w);
}

// ---------------------------------------------------------------------------
// Kernel 1: tA[b, c*H+o] = tanh( sum_h hidden[b,h]*attn_w[c,o,h] + attn_b[c,o] )
// GEMM: M=256, N=16384, K=1024, fp32 in/out, 3-term bf16-split MFMA.
// 128(M)x64(N) tile, 512 threads (8 waves, 4m x 2n, wave 32x32), grid (2,256).
// Software-pipelined register staging: iter k+1's global loads are issued
// right after barrier2 of iter k, so their ~600-900 cy latency overlaps the
// ds_read+MFMA phase instead of stalling at the vmcnt(0) before LDS writes.
// ---------------------------------------------------------------------------
__global__ __launch_bounds__(512) void gemm1_kernel(
    const float* __restrict__ hidden, const float* __restrict__ attn_w,
    const float* __restrict__ attn_b, float* __restrict__ hp)
{
    __shared__ short AsH[128 * RS_];   // [row][k], padded stride
    __shared__ short AsL[128 * RS_];
    __shared__ short BsH[64 * RS_];
    __shared__ short BsL[64 * RS_];

    const int tid  = threadIdx.x;
    const int wave = tid >> 6, lane = tid & 63;
    const int m0 = blockIdx.x * 128;   // 2 m-tiles (fast axis)
    const int n0 = blockIdx.y * 64;    // 256 n-tiles
    const int wm = (wave >> 1) * 32;   // 4x2 wave grid, each wave 32x32
    const int wn = (wave & 1) * 32;
    const int l16 = lane & 15;
    const int lk  = (lane >> 4) * 8;

    f32x4 acc[2][2];
    for (int mi = 0; mi < 2; ++mi)
        for (int ni = 0; ni < 2; ++ni)
            acc[mi][ni] = f32x4{0.f, 0.f, 0.f, 0.f};

    // A-tile: 128x32 = 1024 float4-chunks (2/thread); B-tile: 64x32 = 512 (1/thread)
    int rA[2], cA[2];
    #pragma unroll
    for (int i = 0; i < 2; ++i) {
        const int chunk = tid + i * 512;
        rA[i] = chunk >> 3;
        cA[i] = (chunk & 7) * 4;
    }
    const int rB = tid >> 3, cB = (tid & 7) * 4;

    const float* pA0 = hidden + rA[0] * H_ + m0 * H_ + cA[0];
    const float* pA1 = hidden + rA[1] * H_ + m0 * H_ + cA[1];
    const float* pB  = attn_w + (size_t)(n0 + rB) * HD_ + cB;

    // prologue: load k=0
    float4 va[2], vb;
    va[0] = *(const float4*)(pA0);
    va[1] = *(const float4*)(pA1);
    vb    = *(const float4*)(pB);

    for (int k0 = 0; k0 < H_; k0 += 32) {
        __syncthreads();               // previous iter's fragment reads done
        #pragma unroll
        for (int i = 0; i < 2; ++i) {
            s16x4 h, l;
            split4(va[i], h, l);
            *(s16x4*)(AsH + rA[i] * RS_ + cA[i]) = h;
            *(s16x4*)(AsL + rA[i] * RS_ + cA[i]) = l;
        }
        {
            s16x4 h, l;
            split4(vb, h, l);
            *(s16x4*)(BsH + rB * RS_ + cB) = h;
            *(s16x4*)(BsL + rB * RS_ + cB) = l;
        }
        __syncthreads();               // stores visible to all waves

        // prefetch next K-slab while this slab's MFMAs run
        if (k0 + 32 < H_) {
            const int kn = k0 + 32;
            va[0] = *(const float4*)(pA0 + kn);
            va[1] = *(const float4*)(pA1 + kn);
            vb    = *(const float4*)(pB  + kn);
        }

        short8 ah[2], al[2], bh[2], bl[2];
        #pragma unroll
        for (int mi = 0; mi < 2; ++mi) {
            ah[mi] = *(const short8*)(AsH + (wm + mi * 16 + l16) * RS_ + lk);
            al[mi] = *(const short8*)(AsL + (wm + mi * 16 + l16) * RS_ + lk);
        }
        #pragma unroll
        for (int ni = 0; ni < 2; ++ni) {
            bh[ni] = *(const short8*)(BsH + (wn + ni * 16 + l16) * RS_ + lk);
            bl[ni] = *(const short8*)(BsL + (wn + ni * 16 + l16) * RS_ + lk);
        }
        #pragma unroll
        for (int mi = 0; mi < 2; ++mi)
            #pragma unroll
            for (int ni = 0; ni < 2; ++ni) {
                acc[mi][ni] = MFMA16(ah[mi], bh[ni], acc[mi][ni]);
                acc[mi][ni] = MFMA16(al[mi], bh[ni], acc[mi][ni]);
                acc[mi][ni] = MFMA16(ah[mi], bl[ni], acc[mi][ni]);
            }
    }

    // C/D layout: col = lane&15, row = (lane>>4)*4 + reg.  Store tanh(val).
    const int lr = (lane >> 4) * 4;
    #pragma unroll
    for (int mi = 0; mi < 2; ++mi) {
        #pragma unroll
        for (int ni = 0; ni < 2; ++ni) {
            const int col  = n0 + wn + ni * 16 + l16;
            const float bias = attn_b[col];
            float* dst = hp + (size_t)(m0 + wm + mi * 16 + lr) * N1_ + col;
            f32x4 vacc = acc[mi][ni];
            dst[0]        = tanh_c(vacc[0] + bias);
            dst[N1_]      = tanh_c(vacc[1] + bias);
            dst[2 * N1_]  = tanh_c(vacc[2] + bias);
            dst[3 * N1_]  = tanh_c(vacc[3] + bias);
        }
    }
}

// ---------------------------------------------------------------------------
// Kernel 2: tB[c,g,o] = tanh( sum_d enc[c,g,d] * attn_w[c,o,H+d] )
// Per-c GEMM: M=32, N=1024, K=256; grid (16,16)=256 blocks.
// ---------------------------------------------------------------------------
__global__ __launch_bounds__(256) void gemm2_kernel(
    const float* __restrict__ enc, const float* __restrict__ attn_w,
    float* __restrict__ ep)
{
    const int tid  = threadIdx.x;
    const int wave = tid >> 6, lane = tid & 63;
    const int c  = blockIdx.y;
    const int n0 = blockIdx.x * 64 + wave * 16;   // o tile, 16 per wave
    const int l16 = lane & 15;
    const int lk  = (lane >> 4) * 8;

    f32x4 acc[2];
    acc[0] = f32x4{0.f, 0.f, 0.f, 0.f};
    acc[1] = f32x4{0.f, 0.f, 0.f, 0.f};

    const float* encp = enc + c * (G_ * D_);
    const float* wp   = attn_w + (size_t)c * H_ * HD_ + H_;

    #pragma unroll
    for (int kk = 0; kk < 8; ++kk) {
        const int k0 = kk * 32 + lk;
        short8 ah[2], al[2], bh, bl;
        #pragma unroll
        for (int mi = 0; mi < 2; ++mi) {
            const float* p = encp + (mi * 16 + l16) * D_ + k0;
            s16x4 h0, l0, h1, l1;
            split4(*(const float4*)p, h0, l0);
            split4(*(const float4*)(p + 4), h1, l1);
            ah[mi] = short8{h0[0],h0[1],h0[2],h0[3],h1[0],h1[1],h1[2],h1[3]};
            al[mi] = short8{l0[0],l0[1],l0[2],l0[3],l1[0],l1[1],l1[2],l1[3]};
        }
        {
            const float* p = wp + (size_t)(n0 + l16) * HD_ + k0;
            s16x4 h0, l0, h1, l1;
            split4(*(const float4*)p, h0, l0);
            split4(*(const float4*)(p + 4), h1, l1);
            bh = short8{h0[0],h0[1],h0[2],h0[3],h1[0],h1[1],h1[2],h1[3]};
            bl = short8{l0[0],l0[1],l0[2],l0[3],l1[0],l1[1],l1[2],l1[3]};
        }
        #pragma unroll
        for (int mi = 0; mi < 2; ++mi) {
            acc[mi] = MFMA16(ah[mi], bh, acc[mi]);
            acc[mi] = MFMA16(al[mi], bh, acc[mi]);
            acc[mi] = MFMA16(ah[mi], bl, acc[mi]);
        }
    }

    const int lr = (lane >> 4) * 4;
    #pragma unroll
    for (int mi = 0; mi < 2; ++mi) {
        const int g = mi * 16 + lr;
        const int o = n0 + l16;
        float* dst = ep + (c * G_ + g) * H_ + o;
        f32x4 vacc = acc[mi];
        dst[0]      = tanh_c(vacc[0]);
        dst[H_]     = tanh_c(vacc[1]);
        dst[2 * H_] = tanh_c(vacc[2]);
        dst[3 * H_] = tanh_c(vacc[3]);
    }
}

// ---------------------------------------------------------------------------
// Kernel 3: per (b,c): scores[g] = sum_h blend(tA,tB)*v where
// blend = (tA+tB)/(1+tA*tB) = tanh(A+B) exactly; softmax over g; att_cat out;
// weighted[b,c,d] = sum_g att*enc.  All fp32.
// ---------------------------------------------------------------------------
__global__ __launch_bounds__(256) void attn_kernel(
    const float* __restrict__ hp, const float* __restrict__ ep,
    const float* __restrict__ v, const float* __restrict__ enc,
    float* __restrict__ out, float* __restrict__ wt)
{
    const int c = blockIdx.x, b = blockIdx.y;
    const int tid  = threadIdx.x;
    const int wave = tid >> 6, lane = tid & 63;

    __shared__ float s_att[G_];
    __shared__ float s_sc[G_];

    float tav[16], vv[16];
    const float* hprow = hp + (size_t)b * N1_ + c * H_;
    const float* vrow  = v + c * H_;
    #pragma unroll
    for (int j = 0; j < 16; ++j) {
        const int o = lane + j * 64;
        tav[j] = hprow[o];
        vv[j]  = vrow[o];
    }

    #pragma unroll
    for (int gg = 0; gg < 8; ++gg) {
        const int g = wave * 8 + gg;
        const float* eprow = ep + (c * G_ + g) * H_;
        float s = 0.f;
        #pragma unroll
        for (int j = 0; j < 16; ++j) {
            const float tb  = eprow[lane + j * 64];
            const float ta  = tav[j];
            const float num = ta + tb;
            const float den = fmaf(ta, tb, 1.f);
            const float t   = num * __builtin_amdgcn_rcpf(den);
            s = fmaf(t, vv[j], s);
        }
        #pragma unroll
        for (int off = 32; off > 0; off >>= 1)
            s += __shfl_down(s, off, 64);
        if (lane == 0) s_sc[g] = s;
    }
    __syncthreads();

    if (tid < 32) {
        float s = s_sc[tid];
        float m = s;
        #pragma unroll
        for (int off = 16; off > 0; off >>= 1)
            m = fmaxf(m, __shfl_xor(m, off, 32));
        const float e = __expf(s - m);
        float sum = e;
        #pragma unroll
        for (int off = 16; off > 0; off >>= 1)
            sum += __shfl_xor(sum, off, 32);
        const float a = e / sum;
        s_att[tid] = a;
        out[(size_t)b * (C_ * G_) + c * G_ + tid] = a;   // att_cat
    }
    __syncthreads();

    // weighted[b,c,d], thread = d
    float wsum = 0.f;
    const float* encc = enc + c * (G_ * D_) + tid;
    #pragma unroll
    for (int g = 0; g < G_; ++g)
        wsum += s_att[g] * encc[g * D_];
    wt[(size_t)(b * C_ + c) * D_ + tid] = wsum;
}

// ---------------------------------------------------------------------------
// Kernel 4: pooled[b,d] = mean_c weighted; out[b,o] = pooled.out_w[o,:] + out_b
// ---------------------------------------------------------------------------
__global__ __launch_bounds__(256) void out_kernel(
    const float* __restrict__ wt, const float* __restrict__ out_w,
    const float* __restrict__ out_b, float* __restrict__ out)
{
    const int b = blockIdx.x, tid = threadIdx.x;
    __shared__ float pooled[D_];

    float s = 0.f;
    #pragma unroll
    for (int c = 0; c < C_; ++c)
        s += wt[(size_t)(b * C_ + c) * D_ + tid];
    pooled[tid] = s * (1.f / 16.f);
    __syncthreads();

    float acc = out_b[tid];
    const float* wrow = out_w + tid * D_;
    #pragma unroll 8
    for (int dc = 0; dc < 64; ++dc) {
        float4 w4 = *(const float4*)(wrow + dc * 4);
        acc += pooled[dc * 4 + 0] * w4.x;
        acc += pooled[dc * 4 + 1] * w4.y;
        acc += pooled[dc * 4 + 2] * w4.z;
        acc += pooled[dc * 4 + 3] * w4.w;
    }
    out[(size_t)B_ * (C_ * G_) + b * O_ + tid] = acc;
}

extern "C" void kernel_launch(void* const* d_in, const int* in_sizes, int n_in,
                              void* d_out, int out_size, void* d_ws, size_t ws_size,
                              hipStream_t stream) {
    const float* hidden = (const float*)d_in[0];   // (B,H)     fp32
    const float* enc    = (const float*)d_in[1];   // (C,G,D)   fp32
    const float* attn_w = (const float*)d_in[2];   // (C,H,H+D) fp32
    const float* attn_b = (const float*)d_in[3];   // (C,H)     fp32
    const float* v      = (const float*)d_in[4];   // (C,H)     fp32
    const float* out_w  = (const float*)d_in[5];   // (O,D)     fp32
    const float* out_b  = (const float*)d_in[6];   // (O,)      fp32
    float* out = (float*)d_out;                    // att_cat (B,C*G) ++ out (B,O)

    float* hp = (float*)d_ws;                      // (B, C*H)  tA, fp32: 16.78 MB
    float* ep = hp + (size_t)B_ * N1_;             // (C, G, H) tB, fp32:  2.10 MB
    float* wt = ep + (size_t)C_ * G_ * H_;         // (B, C, D) fp32:      4.19 MB

    gemm1_kernel<<<dim3(2, 256), 512, 0, stream>>>(hidden, attn_w, attn_b, hp);
    gemm2_kernel<<<dim3(16, C_), 256, 0, stream>>>(enc, attn_w, ep);
    attn_kernel<<<dim3(C_, B_), 256, 0, stream>>>(hp, ep, v, enc, out, wt);
    out_kernel<<<B_, 256, 0, stream>>>(wt, out_w, out_b, out);
}